// Round 17
// baseline (83.090 us; speedup 1.0000x reference)
//
#include <hip/hip_runtime.h>
#include <hip/hip_bf16.h>
#include <math.h>

#define NB 2
#define NPTS 4096
#define CH 64
#define PATCH 64

typedef __attribute__((ext_vector_type(8))) short s16x8;
typedef __attribute__((ext_vector_type(4))) short s16x4;
typedef __attribute__((ext_vector_type(4))) float f32x4;
typedef __attribute__((ext_vector_type(4))) unsigned u32x4;

static __device__ __forceinline__ short f2bf(float f) {
    union { __hip_bfloat16 h; short s; } u;
    u.h = __float2bfloat16(f);
    return u.s;
}
static __device__ __forceinline__ float bf2f(unsigned short v) {
    return __uint_as_float(((unsigned)v) << 16);
}

// ---------------------------------------------------------------------------
// Kernel 0 (fused prep):
//   blocks 0..31  : repack weight (64 x 1024 f32) into bf16 MFMA A-fragments
//   blocks 32..63 : pack xyz into float4 with w = |p|^2
//   blocks 64..127: convert signal f32 -> bf16 (sigbf)
// ---------------------------------------------------------------------------
__global__ __launch_bounds__(256) void prep_kernel(const float* __restrict__ W,
                                                   short* __restrict__ Wfrag,
                                                   const float* __restrict__ xyz,
                                                   float4* __restrict__ xyz4,
                                                   const float* __restrict__ signal,
                                                   unsigned short* __restrict__ sigbf) {
    const int bid = blockIdx.x;
    const int tid = threadIdx.x;
    if (bid < 32) {
        const int gid = bid * 256 + tid;          // 8192 total
        const int mt = gid >> 11;
        const int st = (gid >> 6) & 31;
        const int l  = gid & 63;
        const int i  = mt * 16 + (l & 15);
        const int k0 = st * 32 + (l >> 4) * 8;
        const f32x4 a = *(const f32x4*)&W[i * 1024 + k0];
        const f32x4 c = *(const f32x4*)&W[i * 1024 + k0 + 4];
        s16x8 v;
        v[0] = f2bf(a[0]); v[1] = f2bf(a[1]); v[2] = f2bf(a[2]); v[3] = f2bf(a[3]);
        v[4] = f2bf(c[0]); v[5] = f2bf(c[1]); v[6] = f2bf(c[2]); v[7] = f2bf(c[3]);
        *(s16x8*)&Wfrag[gid * 8] = v;
    } else if (bid < 64) {
        const int idx = (bid - 32) * 256 + tid;   // 8192 points
        const float x = xyz[idx * 3 + 0];
        const float y = xyz[idx * 3 + 1];
        const float z = xyz[idx * 3 + 2];
        float4 v;
        v.x = x; v.y = y; v.z = z;
        v.w = fmaf(x, x, fmaf(y, y, z * z));      // |p|^2
        xyz4[idx] = v;
    } else {
        const int g = (bid - 64) * 256 + tid;     // 16384 threads x 32 floats
        const size_t base = (size_t)g * 32;
#pragma unroll
        for (int u = 0; u < 8; ++u) {
            const f32x4 v = *(const f32x4*)&signal[base + u * 4];
            s16x4 o;
            o[0] = f2bf(v[0]); o[1] = f2bf(v[1]); o[2] = f2bf(v[2]); o[3] = f2bf(v[3]);
            *(s16x4*)&sigbf[base + u * 4] = o;
        }
    }
}

// ---------------------------------------------------------------------------
// Kernel 1: exact 64-NN. r15 structure + two instruction diets:
//   - UNPACKED u32 hist[4096] (16 KB): 1-op atomicAdd vs 4-op packed chain;
//     scan loses the shift/mask unpack. LDS 25 KB -> 6 blocks/CU (r15's
//     8-deep ILP hides latency in-wave, so occupancy matters less).
//   - dot-form distance (|p|^2 - 2 p.q + |q|^2): 5 ops vs 6; SAME formula
//     in both passes -> bit-identical keys (and it's the reference's own
//     cdist form).
// ---------------------------------------------------------------------------
__global__ __launch_bounds__(256, 6) void knn_kernel(const float4* __restrict__ xyz4,
                                                     int* __restrict__ knn_idx) {
    const int pt   = blockIdx.x;
    const int b    = pt >> 12;
    const int q    = pt & (NPTS - 1);
    const int tid  = threadIdx.x;
    const int wv   = tid >> 6;
    const int lane = tid & 63;

    __shared__ __align__(16) unsigned hist[4096];        // 16 KB; -> cand
    __shared__ __align__(16) unsigned short sbin[4096];  // 8 KB
    __shared__ unsigned wsum[4];
    __shared__ unsigned sh_H;
    __shared__ int sh_need;
    __shared__ int cnt_less, cnt_tie;

    const float4* xb = xyz4 + (size_t)b * NPTS;
    const float4 qp = xb[q];
    const float m2x = -2.0f * qp.x, m2y = -2.0f * qp.y, m2z = -2.0f * qp.z;
    const float qw = qp.w;

#pragma unroll
    for (int u = 0; u < 4; ++u)
        ((u32x4*)hist)[u * 256 + tid] = (u32x4){0u, 0u, 0u, 0u};
    if (tid == 0) { cnt_less = 0; cnt_tie = 0; }
    __syncthreads();

    // ---- single distance pass: 8-deep batched loads, bin -> LDS + hist ----
    auto eval1 = [&](const float4 p, const int m) {
        float t = fmaf(p.x, m2x, p.w);
        t = fmaf(p.y, m2y, t);
        t = fmaf(p.z, m2z, t);
        t = fmaxf(t + qw, 0.0f);
        const unsigned hk = __float_as_uint(t) >> 19;    // 0..4095
        sbin[m] = (unsigned short)hk;
        atomicAdd(&hist[hk], 1u);
    };
#pragma unroll 1
    for (int i = 0; i < 2; ++i) {
        const int m = i * 2048 + tid;
        const float4 p0 = xb[m];
        const float4 p1 = xb[m + 256];
        const float4 p2 = xb[m + 512];
        const float4 p3 = xb[m + 768];
        const float4 p4 = xb[m + 1024];
        const float4 p5 = xb[m + 1280];
        const float4 p6 = xb[m + 1536];
        const float4 p7 = xb[m + 1792];
        eval1(p0, m);        eval1(p1, m + 256);
        eval1(p2, m + 512);  eval1(p3, m + 768);
        eval1(p4, m + 1024); eval1(p5, m + 1280);
        eval1(p6, m + 1536); eval1(p7, m + 1792);
    }
    __syncthreads();

    // ---- scan: thread t owns bins [16t, 16t+16) ----
    unsigned tsum = 0;
#pragma unroll
    for (int u = 0; u < 4; ++u) {
        const u32x4 h4 = ((const u32x4*)hist)[tid * 4 + u];
        tsum += h4[0] + h4[1] + h4[2] + h4[3];
    }
    unsigned run = tsum;
#pragma unroll
    for (int off = 1; off < 64; off <<= 1) {
        const unsigned v = __shfl_up(run, off);
        if (lane >= off) run += v;
    }
    if (lane == 63) wsum[wv] = run;
    __syncthreads();
    unsigned wbase = 0;
    for (int w2 = 0; w2 < wv; ++w2) wbase += wsum[w2];
    const unsigned incl = wbase + run;
    const unsigned excl = incl - tsum;
    if ((int)excl < PATCH && PATCH <= (int)incl) {   // unique crossing thread
        int nrem = PATCH - (int)excl;
        for (int u = 0; u < 16; ++u) {
            const unsigned cb = hist[tid * 16 + u];
            if (nrem <= (int)cb) { sh_H = (unsigned)(tid * 16 + u); sh_need = nrem; break; }
            nrem -= (int)cb;
        }
    }
    __syncthreads();

    const unsigned H = sh_H;
    const int need  = sh_need;
    const int nless = PATCH - need;
    int* optr = knn_idx + (size_t)pt * PATCH;
    unsigned* ckey = hist;            // hist dead after scan -> candidate buf
    unsigned* cidx = hist + 1024;

    // ---- extraction from cached bins: 8-deep batched sbin reads ----
    auto extr1 = [&](const unsigned hk, const int m) {
        if (hk < H) {
            const int pos = atomicAdd(&cnt_less, 1);
            optr[pos] = m;
        } else if (hk == H) {
            const int pos = atomicAdd(&cnt_tie, 1);
            if (pos < 1024) {
                const float4 p = xb[m];      // rare: recompute exact key
                float t = fmaf(p.x, m2x, p.w);
                t = fmaf(p.y, m2y, t);
                t = fmaf(p.z, m2z, t);
                t = fmaxf(t + qw, 0.0f);
                ckey[pos] = __float_as_uint(t);
                cidx[pos] = (unsigned)m;
            }
        }
    };
#pragma unroll 1
    for (int i = 0; i < 2; ++i) {
        const int m = i * 2048 + tid;
        const unsigned h0 = sbin[m];
        const unsigned h1 = sbin[m + 256];
        const unsigned h2 = sbin[m + 512];
        const unsigned h3 = sbin[m + 768];
        const unsigned h4 = sbin[m + 1024];
        const unsigned h5 = sbin[m + 1280];
        const unsigned h6 = sbin[m + 1536];
        const unsigned h7 = sbin[m + 1792];
        extr1(h0, m);        extr1(h1, m + 256);
        extr1(h2, m + 512);  extr1(h3, m + 768);
        extr1(h4, m + 1024); extr1(h5, m + 1280);
        extr1(h6, m + 1536); extr1(h7, m + 1792);
    }
    __syncthreads();

    // ---- exact rank-select within boundary bin (nc typically ~6) ----
    const int nc = min(cnt_tie, 1024);
    for (int i = tid; i < nc; i += 256) {
        const unsigned ki = ckey[i];
        const unsigned mi = cidx[i];
        int rank = 0;
        for (int j = 0; j < nc; ++j) {          // uniform j -> LDS broadcast
            const unsigned kj = ckey[j];
            const unsigned mj = cidx[j];
            rank += (kj < ki || (kj == ki && mj < mi)) ? 1 : 0;
        }
        if (rank < need) optr[nless + rank] = (int)mi;
    }
}

// ---------------------------------------------------------------------------
// Kernel 2: conv, SH-parallel, sigF-free (r16 version — unchanged).
// ---------------------------------------------------------------------------
__global__ __launch_bounds__(256, 5) void conv_kernel(const float4* __restrict__ xyz4,
                                                      const unsigned short* __restrict__ sigbf,
                                                      const short* __restrict__ Wfrag,
                                                      const float* __restrict__ biases,
                                                      const int* __restrict__ knn_idx,
                                                      float* __restrict__ out) {
    const int tid  = threadIdx.x;
    const int wv   = tid >> 6;
    const int lane = tid & 63;
    const int ln15 = lane & 15;
    const int kq   = lane >> 4;

    __shared__ __align__(16) short Y4[4 * 64 * 20];   // 10 KB, stride 20
    __shared__ __align__(16) float rad4[4 * 64 * 4];  // 4 KB
    __shared__ __align__(16) short ckF[4096];         // 8 KB  A-fragment order
    __shared__ __align__(16) short zb[4 * 1032];      // 8.25 KB z rows (bf16)
    __shared__ int   sIdx4[256];                      // 1 KB
    __shared__ float sh_inv4[4];

    sIdx4[tid] = knn_idx[(size_t)blockIdx.x * 256 + tid];
    __syncthreads();   // A0

    const int b = blockIdx.x >> 10;
    const float4* xbase = xyz4 + (size_t)b * NPTS;
    const unsigned short* sgb = sigbf + (size_t)b * NPTS * CH;

    // ---- phase A: SH + radial for point wv, neighbor lane ----
    {
        const int q   = (blockIdx.x * 4 + wv) & (NPTS - 1);
        const int idx = sIdx4[wv * 64 + lane];
        const float4 cp = xbase[q];
        const float4 np = xbase[idx];
        const float dx = np.x - cp.x;
        const float dy = np.y - cp.y;
        const float dz = np.z - cp.z;
        const float nrm2 = dx * dx + dy * dy + dz * dz;
        const float inv_n = 1.0f / fmaxf(sqrtf(nrm2), 0.01f);
        const float x = dx * inv_n, y = dy * inv_n, z = dz * inv_n;
        const float x2 = x * x, y2 = y * y, zz = z * z;

        float Y[16];
        Y[0] = 0.28209479177387814f;
        const float s3 = 0.4886025119029199f;
        Y[1] = s3 * y;  Y[2] = s3 * z;  Y[3] = -s3 * x;
        const float s15h = 1.0925484305920792f;
        const float s15q = 0.5462742152960396f;
        const float s5q  = 0.31539156525252005f;
        Y[4] = s15h * x * y;
        Y[5] = s15h * y * z;
        Y[6] = s5q * (2.0f * zz - x2 - y2);
        Y[7] = -s15h * z * x;
        Y[8] = s15q * (x2 - y2);
        const float c33  = 0.5900435899266435f;
        const float c32  = 2.8906114426405543f;
        const float c31  = 0.4570457994644658f;
        const float c30  = 0.3731763325901154f;
        const float c32b = 1.4453057213202771f;
        Y[9]  = c33 * (3.0f * x2 * y - y * y2);
        Y[10] = c32 * x * y * z;
        Y[11] = c31 * (4.0f * y * zz - x2 * y - y * y2);
        Y[12] = c30 * (2.0f * z * zz - 3.0f * x2 * z - 3.0f * y2 * z);
        Y[13] = -c31 * (4.0f * zz * x - x * x2 - x * y2);
        Y[14] = c32b * (x2 * z - y2 * z);
        Y[15] = -c33 * (x * x2 - 3.0f * x * y2);

        const float dist = sqrtf(fmaxf(nrm2, 1e-4f));
        const float d1 = dist - 0.16666667f;
        const float d2 = dist - 0.33333334f;
        const float d3 = dist - 0.5f;
        f32x4 rad;
        rad[0] = expf(-dist * dist * 18.0f);
        rad[1] = expf(-d1 * d1 * 18.0f);
        rad[2] = expf(-d2 * d2 * 18.0f);
        rad[3] = expf(-d3 * d3 * 18.0f);

        const int ybase = (wv * 64 + lane) * 20;
#pragma unroll
        for (int k4 = 0; k4 < 4; ++k4) {
            s16x4 v;
            v[0] = f2bf(Y[k4 * 4 + 0]);
            v[1] = f2bf(Y[k4 * 4 + 1]);
            v[2] = f2bf(Y[k4 * 4 + 2]);
            v[3] = f2bf(Y[k4 * 4 + 3]);
            *(s16x4*)&Y4[ybase + k4 * 4] = v;
        }
        *(f32x4*)&rad4[(wv * 64 + lane) * 4] = rad;

        float v = 0.28209479177387814f * rad[0];
#pragma unroll
        for (int off = 32; off > 0; off >>= 1) v += __shfl_down(v, off);
        if (lane == 0) sh_inv4[wv] = 1.0f / (v + 1e-6f);
    }
    __syncthreads();   // A1

    for (int it = 0; it < 4; ++it) {
        // ---- gather own B-fragments straight to registers (ct = wv) ----
        s16x8 bf0, bf1;
        {
            const int rb = it * 64 + kq * 8;
#pragma unroll
            for (int j = 0; j < 8; ++j) {
                const unsigned short* rp =
                    sgb + ((size_t)sIdx4[rb + j] << 6) + wv * 16 + ln15;
                bf0[j] = (short)rp[0];
            }
#pragma unroll
            for (int j = 0; j < 8; ++j) {
                const unsigned short* rp =
                    sgb + ((size_t)sIdx4[rb + 32 + j] << 6) + wv * 16 + ln15;
                bf1[j] = (short)rp[0];
            }
        }
        // ---- ckF build: fragments f = wv, wv+4; ck = Y[ln15]*rad[mt] ----
#pragma unroll
        for (int ff = 0; ff < 2; ++ff) {
            const int f  = wv + ff * 4;
            const int mt = f >> 1, s = f & 1;
            const int pb = s * 32 + kq * 8;
            s16x8 av;
#pragma unroll
            for (int j = 0; j < 8; ++j) {
                const int p = pb + j;
                const float Yv = bf2f((unsigned short)Y4[(it * 64 + p) * 20 + ln15]);
                const float rv = rad4[(it * 64 + p) * 4 + mt];
                av[j] = f2bf(Yv * rv);
            }
            *(s16x8*)&ckF[f * 512 + lane * 8] = av;
        }
        __syncthreads();   // B1: ckF ready (bf0/bf1 are registers)

        // ---- MFMA main matmul; wave wv owns c-tile ct=wv ----
        f32x4 acc0 = {0.f, 0.f, 0.f, 0.f}, acc1 = acc0, acc2 = acc0, acc3 = acc0;
        {
            s16x8 a;
            a = *(const s16x8*)&ckF[0 * 512 + lane * 8];
            acc0 = __builtin_amdgcn_mfma_f32_16x16x32_bf16(a, bf0, acc0, 0, 0, 0);
            a = *(const s16x8*)&ckF[1 * 512 + lane * 8];
            acc0 = __builtin_amdgcn_mfma_f32_16x16x32_bf16(a, bf1, acc0, 0, 0, 0);
            a = *(const s16x8*)&ckF[2 * 512 + lane * 8];
            acc1 = __builtin_amdgcn_mfma_f32_16x16x32_bf16(a, bf0, acc1, 0, 0, 0);
            a = *(const s16x8*)&ckF[3 * 512 + lane * 8];
            acc1 = __builtin_amdgcn_mfma_f32_16x16x32_bf16(a, bf1, acc1, 0, 0, 0);
            a = *(const s16x8*)&ckF[4 * 512 + lane * 8];
            acc2 = __builtin_amdgcn_mfma_f32_16x16x32_bf16(a, bf0, acc2, 0, 0, 0);
            a = *(const s16x8*)&ckF[5 * 512 + lane * 8];
            acc2 = __builtin_amdgcn_mfma_f32_16x16x32_bf16(a, bf1, acc2, 0, 0, 0);
            a = *(const s16x8*)&ckF[6 * 512 + lane * 8];
            acc3 = __builtin_amdgcn_mfma_f32_16x16x32_bf16(a, bf0, acc3, 0, 0, 0);
            a = *(const s16x8*)&ckF[7 * 512 + lane * 8];
            acc3 = __builtin_amdgcn_mfma_f32_16x16x32_bf16(a, bf1, acc3, 0, 0, 0);
        }

        // ---- band-sum (xor-reduce over k-quads), z row -> zb ----
        const float inv = sh_inv4[it];
        const int qq = kq;
        float rb[4][4];
#pragma unroll
        for (int mt = 0; mt < 4; ++mt) {
            f32x4 av = (mt == 0) ? acc0 : (mt == 1) ? acc1 : (mt == 2) ? acc2 : acc3;
            const float y0 = av[0] * inv, y1 = av[1] * inv;
            const float y2 = av[2] * inv, y3 = av[3] * inv;
            const float sA = y0 * y0;
            const float sB = y1 * y1 + y2 * y2 + y3 * y3;
            const float sAll = sA + sB;
            float b0 = (qq == 0) ? sA : 0.0f;
            float b1 = (qq == 0) ? sB : 0.0f;
            float b2 = (qq == 1) ? sAll : ((qq == 2) ? sA : 0.0f);
            float b3 = (qq == 3) ? sAll : ((qq == 2) ? sB : 0.0f);
            b0 += __shfl_xor(b0, 16); b0 += __shfl_xor(b0, 32);
            b1 += __shfl_xor(b1, 16); b1 += __shfl_xor(b1, 32);
            b2 += __shfl_xor(b2, 16); b2 += __shfl_xor(b2, 32);
            b3 += __shfl_xor(b3, 16); b3 += __shfl_xor(b3, 32);
            rb[mt][0] = b0; rb[mt][1] = b1; rb[mt][2] = b2; rb[mt][3] = b3;
        }
        float s0 = rb[0][0], s1 = rb[0][1], s2 = rb[0][2], s3 = rb[0][3];
#pragma unroll
        for (int mt = 1; mt < 4; ++mt) {
            s0 = (qq == mt) ? rb[mt][0] : s0;
            s1 = (qq == mt) ? rb[mt][1] : s1;
            s2 = (qq == mt) ? rb[mt][2] : s2;
            s3 = (qq == mt) ? rb[mt][3] : s3;
        }
        s16x4 zv;
        zv[0] = f2bf(sqrtf(fmaxf(s0, 1e-4f)));
        zv[1] = f2bf(sqrtf(fmaxf(s1, 1e-4f)));
        zv[2] = f2bf(sqrtf(fmaxf(s2, 1e-4f)));
        zv[3] = f2bf(sqrtf(fmaxf(s3, 1e-4f)));
        const int c = wv * 16 + ln15;
        *(s16x4*)&zb[it * 1032 + c * 16 + qq * 4] = zv;

        if (it < 3) __syncthreads();   // protect ckF overwrite
    }
    __syncthreads();   // all z rows ready

    // ---- epilogue: out[i] = sum_j W[i][j] z[j] via MFMA, 4 points batched ----
    const int mt5 = wv;
    const int g   = ln15 & 3;
    f32x4 acc5 = {0.f, 0.f, 0.f, 0.f};
#pragma unroll 4
    for (int st = 0; st < 32; ++st) {
        const s16x8 a  = *(const s16x8*)&Wfrag[((mt5 * 32 + st) * 64 + lane) * 8];
        const s16x8 zf = *(const s16x8*)&zb[g * 1032 + st * 32 + kq * 8];
        acc5 = __builtin_amdgcn_mfma_f32_16x16x32_bf16(a, zf, acc5, 0, 0, 0);
    }
    if (ln15 < 4) {
        const int i0 = mt5 * 16 + kq * 4;
        const int orow = (blockIdx.x * 4 + g) * CH;
#pragma unroll
        for (int rg = 0; rg < 4; ++rg)
            out[orow + i0 + rg] = acc5[rg] + biases[i0 + rg];
    }
}

extern "C" void kernel_launch(void* const* d_in, const int* in_sizes, int n_in,
                              void* d_out, int out_size, void* d_ws, size_t ws_size,
                              hipStream_t stream) {
    const float* xyz    = (const float*)d_in[0];
    const float* signal = (const float*)d_in[1];
    const float* weight = (const float*)d_in[2];
    const float* biases = (const float*)d_in[3];
    float* out = (float*)d_out;

    char* ws = (char*)d_ws;
    int*            knn_idx = (int*)ws;                          // 2 MB
    short*          Wfrag   = (short*)(ws + 0x200000);           // 128 KB
    float4*         xyz4    = (float4*)(ws + 0x220000);          // 128 KB
    unsigned short* sigbf   = (unsigned short*)(ws + 0x240000);  // 1 MB

    prep_kernel<<<128, 256, 0, stream>>>(weight, Wfrag, xyz, xyz4, signal, sigbf);
    knn_kernel<<<NB * NPTS, 256, 0, stream>>>(xyz4, knn_idx);
    conv_kernel<<<(NB * NPTS) / 4, 256, 0, stream>>>(xyz4, sigbf, Wfrag, biases,
                                                     knn_idx, out);
}

// Round 18
// 76.326 us; speedup vs baseline: 1.0886x; 1.0886x over previous
//
#include <hip/hip_runtime.h>
#include <hip/hip_bf16.h>
#include <math.h>

#define NB 2
#define NPTS 4096
#define CH 64
#define PATCH 64

typedef __attribute__((ext_vector_type(8))) short s16x8;
typedef __attribute__((ext_vector_type(4))) short s16x4;
typedef __attribute__((ext_vector_type(4))) float f32x4;
typedef __attribute__((ext_vector_type(4))) unsigned u32x4;

static __device__ __forceinline__ short f2bf(float f) {
    union { __hip_bfloat16 h; short s; } u;
    u.h = __float2bfloat16(f);
    return u.s;
}
static __device__ __forceinline__ float bf2f(unsigned short v) {
    return __uint_as_float(((unsigned)v) << 16);
}

// ---------------------------------------------------------------------------
// Kernel 0 (fused prep):
//   blocks 0..31  : repack weight (64 x 1024 f32) into bf16 MFMA A-fragments
//   blocks 32..63 : pack xyz into float4 with w = |p|^2
//   blocks 64..127: convert signal f32 -> bf16 (sigbf)
// ---------------------------------------------------------------------------
__global__ __launch_bounds__(256) void prep_kernel(const float* __restrict__ W,
                                                   short* __restrict__ Wfrag,
                                                   const float* __restrict__ xyz,
                                                   float4* __restrict__ xyz4,
                                                   const float* __restrict__ signal,
                                                   unsigned short* __restrict__ sigbf) {
    const int bid = blockIdx.x;
    const int tid = threadIdx.x;
    if (bid < 32) {
        const int gid = bid * 256 + tid;          // 8192 total
        const int mt = gid >> 11;
        const int st = (gid >> 6) & 31;
        const int l  = gid & 63;
        const int i  = mt * 16 + (l & 15);
        const int k0 = st * 32 + (l >> 4) * 8;
        const f32x4 a = *(const f32x4*)&W[i * 1024 + k0];
        const f32x4 c = *(const f32x4*)&W[i * 1024 + k0 + 4];
        s16x8 v;
        v[0] = f2bf(a[0]); v[1] = f2bf(a[1]); v[2] = f2bf(a[2]); v[3] = f2bf(a[3]);
        v[4] = f2bf(c[0]); v[5] = f2bf(c[1]); v[6] = f2bf(c[2]); v[7] = f2bf(c[3]);
        *(s16x8*)&Wfrag[gid * 8] = v;
    } else if (bid < 64) {
        const int idx = (bid - 32) * 256 + tid;   // 8192 points
        const float x = xyz[idx * 3 + 0];
        const float y = xyz[idx * 3 + 1];
        const float z = xyz[idx * 3 + 2];
        float4 v;
        v.x = x; v.y = y; v.z = z;
        v.w = fmaf(x, x, fmaf(y, y, z * z));      // |p|^2
        xyz4[idx] = v;
    } else {
        const int g = (bid - 64) * 256 + tid;     // 16384 threads x 32 floats
        const size_t base = (size_t)g * 32;
#pragma unroll
        for (int u = 0; u < 8; ++u) {
            const f32x4 v = *(const f32x4*)&signal[base + u * 4];
            s16x4 o;
            o[0] = f2bf(v[0]); o[1] = f2bf(v[1]); o[2] = f2bf(v[2]); o[3] = f2bf(v[3]);
            *(s16x4*)&sigbf[base + u * 4] = o;
        }
    }
}

// ---------------------------------------------------------------------------
// Kernel 1: exact 64-NN (r16 version — measured best).
//   - packed u16 hist[2048] (8 KB) + u16 sbin cache (8 KB) -> 8 blocks/CU
//   - 8-deep batched loads (ILP over L2 latency)
//   - 12-bit bins key>>19; exact boundary rank-select
// ---------------------------------------------------------------------------
__global__ __launch_bounds__(256, 8) void knn_kernel(const float4* __restrict__ xyz4,
                                                     int* __restrict__ knn_idx) {
    const int pt   = blockIdx.x;
    const int b    = pt >> 12;
    const int q    = pt & (NPTS - 1);
    const int tid  = threadIdx.x;
    const int wv   = tid >> 6;
    const int lane = tid & 63;

    __shared__ __align__(16) unsigned hist[2048];        // 8 KB packed; -> cand
    __shared__ __align__(16) unsigned short sbin[4096];  // 8 KB
    __shared__ unsigned wsum[4];
    __shared__ unsigned sh_H;
    __shared__ int sh_need;
    __shared__ int cnt_less, cnt_tie;

    const float4* xb = xyz4 + (size_t)b * NPTS;
    const float4 qp = xb[q];

#pragma unroll
    for (int u = 0; u < 2; ++u)
        ((u32x4*)hist)[u * 256 + tid] = (u32x4){0u, 0u, 0u, 0u};
    if (tid == 0) { cnt_less = 0; cnt_tie = 0; }
    __syncthreads();

    // ---- single distance pass: 8-deep batched loads, bin -> LDS + hist ----
    auto eval1 = [&](const float4 p, const int m) {
        const float dx = p.x - qp.x;
        const float dy = p.y - qp.y;
        const float dz = p.z - qp.z;
        const float sq = fmaf(dx, dx, fmaf(dy, dy, dz * dz));
        const unsigned hk = __float_as_uint(sq) >> 19;   // 0..4095
        sbin[m] = (unsigned short)hk;
        atomicAdd(&hist[hk & 2047], 1u << ((hk >> 11) << 4));
    };
#pragma unroll 1
    for (int i = 0; i < 2; ++i) {
        const int m = i * 2048 + tid;
        const float4 p0 = xb[m];
        const float4 p1 = xb[m + 256];
        const float4 p2 = xb[m + 512];
        const float4 p3 = xb[m + 768];
        const float4 p4 = xb[m + 1024];
        const float4 p5 = xb[m + 1280];
        const float4 p6 = xb[m + 1536];
        const float4 p7 = xb[m + 1792];
        eval1(p0, m);        eval1(p1, m + 256);
        eval1(p2, m + 512);  eval1(p3, m + 768);
        eval1(p4, m + 1024); eval1(p5, m + 1280);
        eval1(p6, m + 1536); eval1(p7, m + 1792);
    }
    __syncthreads();

    // ---- scan: thread t owns bins [16t, 16t+16) (lo/hi halves) ----
    const int wb2 = (tid & 127) * 16;
    const int shp = (tid >> 7) << 4;
    unsigned tsum = 0;
#pragma unroll
    for (int u = 0; u < 4; ++u) {
        const u32x4 h4 = *(const u32x4*)&hist[wb2 + u * 4];
        tsum += ((h4[0] >> shp) & 0xFFFFu) + ((h4[1] >> shp) & 0xFFFFu)
              + ((h4[2] >> shp) & 0xFFFFu) + ((h4[3] >> shp) & 0xFFFFu);
    }
    unsigned run = tsum;
#pragma unroll
    for (int off = 1; off < 64; off <<= 1) {
        const unsigned v = __shfl_up(run, off);
        if (lane >= off) run += v;
    }
    if (lane == 63) wsum[wv] = run;
    __syncthreads();
    unsigned wbase = 0;
    for (int w2 = 0; w2 < wv; ++w2) wbase += wsum[w2];
    const unsigned incl = wbase + run;
    const unsigned excl = incl - tsum;
    if ((int)excl < PATCH && PATCH <= (int)incl) {   // unique crossing thread
        int nrem = PATCH - (int)excl;
        for (int u = 0; u < 16; ++u) {
            const unsigned cb = (hist[wb2 + u] >> shp) & 0xFFFFu;
            if (nrem <= (int)cb) { sh_H = (unsigned)(tid * 16 + u); sh_need = nrem; break; }
            nrem -= (int)cb;
        }
    }
    __syncthreads();

    const unsigned H = sh_H;
    const int need  = sh_need;
    const int nless = PATCH - need;
    int* optr = knn_idx + (size_t)pt * PATCH;
    unsigned* ckey = hist;            // reuse histogram LDS for candidates
    unsigned* cidx = hist + 1024;

    // ---- extraction from cached bins: 8-deep batched sbin reads ----
    auto extr1 = [&](const unsigned hk, const int m) {
        if (hk < H) {
            const int pos = atomicAdd(&cnt_less, 1);
            optr[pos] = m;
        } else if (hk == H) {
            const int pos = atomicAdd(&cnt_tie, 1);
            if (pos < 1024) {
                const float4 p = xb[m];      // rare: recompute exact key
                const float dx = p.x - qp.x;
                const float dy = p.y - qp.y;
                const float dz = p.z - qp.z;
                const float sq = fmaf(dx, dx, fmaf(dy, dy, dz * dz));
                ckey[pos] = __float_as_uint(sq);
                cidx[pos] = m;
            }
        }
    };
#pragma unroll 1
    for (int i = 0; i < 2; ++i) {
        const int m = i * 2048 + tid;
        const unsigned h0 = sbin[m];
        const unsigned h1 = sbin[m + 256];
        const unsigned h2 = sbin[m + 512];
        const unsigned h3 = sbin[m + 768];
        const unsigned h4 = sbin[m + 1024];
        const unsigned h5 = sbin[m + 1280];
        const unsigned h6 = sbin[m + 1536];
        const unsigned h7 = sbin[m + 1792];
        extr1(h0, m);        extr1(h1, m + 256);
        extr1(h2, m + 512);  extr1(h3, m + 768);
        extr1(h4, m + 1024); extr1(h5, m + 1280);
        extr1(h6, m + 1536); extr1(h7, m + 1792);
    }
    __syncthreads();

    // ---- exact rank-select within boundary bin (nc typically ~6) ----
    const int nc = min(cnt_tie, 1024);
    for (int i = tid; i < nc; i += 256) {
        const unsigned ki = ckey[i];
        int rank = 0;
        for (int j = 0; j < nc; ++j) {          // uniform j -> LDS broadcast
            const unsigned kj = ckey[j];
            rank += (kj < ki || (kj == ki && j < i)) ? 1 : 0;
        }
        if (rank < need) optr[nless + rank] = cidx[i];
    }
}

// ---------------------------------------------------------------------------
// Kernel 2: conv, SH-parallel, sigF-free (r16 version — measured best).
// ---------------------------------------------------------------------------
__global__ __launch_bounds__(256, 5) void conv_kernel(const float4* __restrict__ xyz4,
                                                      const unsigned short* __restrict__ sigbf,
                                                      const short* __restrict__ Wfrag,
                                                      const float* __restrict__ biases,
                                                      const int* __restrict__ knn_idx,
                                                      float* __restrict__ out) {
    const int tid  = threadIdx.x;
    const int wv   = tid >> 6;
    const int lane = tid & 63;
    const int ln15 = lane & 15;
    const int kq   = lane >> 4;

    __shared__ __align__(16) short Y4[4 * 64 * 20];   // 10 KB, stride 20
    __shared__ __align__(16) float rad4[4 * 64 * 4];  // 4 KB
    __shared__ __align__(16) short ckF[4096];         // 8 KB  A-fragment order
    __shared__ __align__(16) short zb[4 * 1032];      // 8.25 KB z rows (bf16)
    __shared__ int   sIdx4[256];                      // 1 KB
    __shared__ float sh_inv4[4];

    sIdx4[tid] = knn_idx[(size_t)blockIdx.x * 256 + tid];
    __syncthreads();   // A0

    const int b = blockIdx.x >> 10;
    const float4* xbase = xyz4 + (size_t)b * NPTS;
    const unsigned short* sgb = sigbf + (size_t)b * NPTS * CH;

    // ---- phase A: SH + radial for point wv, neighbor lane ----
    {
        const int q   = (blockIdx.x * 4 + wv) & (NPTS - 1);
        const int idx = sIdx4[wv * 64 + lane];
        const float4 cp = xbase[q];
        const float4 np = xbase[idx];
        const float dx = np.x - cp.x;
        const float dy = np.y - cp.y;
        const float dz = np.z - cp.z;
        const float nrm2 = dx * dx + dy * dy + dz * dz;
        const float inv_n = 1.0f / fmaxf(sqrtf(nrm2), 0.01f);
        const float x = dx * inv_n, y = dy * inv_n, z = dz * inv_n;
        const float x2 = x * x, y2 = y * y, zz = z * z;

        float Y[16];
        Y[0] = 0.28209479177387814f;
        const float s3 = 0.4886025119029199f;
        Y[1] = s3 * y;  Y[2] = s3 * z;  Y[3] = -s3 * x;
        const float s15h = 1.0925484305920792f;
        const float s15q = 0.5462742152960396f;
        const float s5q  = 0.31539156525252005f;
        Y[4] = s15h * x * y;
        Y[5] = s15h * y * z;
        Y[6] = s5q * (2.0f * zz - x2 - y2);
        Y[7] = -s15h * z * x;
        Y[8] = s15q * (x2 - y2);
        const float c33  = 0.5900435899266435f;
        const float c32  = 2.8906114426405543f;
        const float c31  = 0.4570457994644658f;
        const float c30  = 0.3731763325901154f;
        const float c32b = 1.4453057213202771f;
        Y[9]  = c33 * (3.0f * x2 * y - y * y2);
        Y[10] = c32 * x * y * z;
        Y[11] = c31 * (4.0f * y * zz - x2 * y - y * y2);
        Y[12] = c30 * (2.0f * z * zz - 3.0f * x2 * z - 3.0f * y2 * z);
        Y[13] = -c31 * (4.0f * zz * x - x * x2 - x * y2);
        Y[14] = c32b * (x2 * z - y2 * z);
        Y[15] = -c33 * (x * x2 - 3.0f * x * y2);

        const float dist = sqrtf(fmaxf(nrm2, 1e-4f));
        const float d1 = dist - 0.16666667f;
        const float d2 = dist - 0.33333334f;
        const float d3 = dist - 0.5f;
        f32x4 rad;
        rad[0] = expf(-dist * dist * 18.0f);
        rad[1] = expf(-d1 * d1 * 18.0f);
        rad[2] = expf(-d2 * d2 * 18.0f);
        rad[3] = expf(-d3 * d3 * 18.0f);

        const int ybase = (wv * 64 + lane) * 20;
#pragma unroll
        for (int k4 = 0; k4 < 4; ++k4) {
            s16x4 v;
            v[0] = f2bf(Y[k4 * 4 + 0]);
            v[1] = f2bf(Y[k4 * 4 + 1]);
            v[2] = f2bf(Y[k4 * 4 + 2]);
            v[3] = f2bf(Y[k4 * 4 + 3]);
            *(s16x4*)&Y4[ybase + k4 * 4] = v;
        }
        *(f32x4*)&rad4[(wv * 64 + lane) * 4] = rad;

        float v = 0.28209479177387814f * rad[0];
#pragma unroll
        for (int off = 32; off > 0; off >>= 1) v += __shfl_down(v, off);
        if (lane == 0) sh_inv4[wv] = 1.0f / (v + 1e-6f);
    }
    __syncthreads();   // A1

    for (int it = 0; it < 4; ++it) {
        // ---- gather own B-fragments straight to registers (ct = wv) ----
        s16x8 bf0, bf1;
        {
            const int rb = it * 64 + kq * 8;
#pragma unroll
            for (int j = 0; j < 8; ++j) {
                const unsigned short* rp =
                    sgb + ((size_t)sIdx4[rb + j] << 6) + wv * 16 + ln15;
                bf0[j] = (short)rp[0];
            }
#pragma unroll
            for (int j = 0; j < 8; ++j) {
                const unsigned short* rp =
                    sgb + ((size_t)sIdx4[rb + 32 + j] << 6) + wv * 16 + ln15;
                bf1[j] = (short)rp[0];
            }
        }
        // ---- ckF build: fragments f = wv, wv+4; ck = Y[ln15]*rad[mt] ----
#pragma unroll
        for (int ff = 0; ff < 2; ++ff) {
            const int f  = wv + ff * 4;
            const int mt = f >> 1, s = f & 1;
            const int pb = s * 32 + kq * 8;
            s16x8 av;
#pragma unroll
            for (int j = 0; j < 8; ++j) {
                const int p = pb + j;
                const float Yv = bf2f((unsigned short)Y4[(it * 64 + p) * 20 + ln15]);
                const float rv = rad4[(it * 64 + p) * 4 + mt];
                av[j] = f2bf(Yv * rv);
            }
            *(s16x8*)&ckF[f * 512 + lane * 8] = av;
        }
        __syncthreads();   // B1: ckF ready (bf0/bf1 are registers)

        // ---- MFMA main matmul; wave wv owns c-tile ct=wv ----
        f32x4 acc0 = {0.f, 0.f, 0.f, 0.f}, acc1 = acc0, acc2 = acc0, acc3 = acc0;
        {
            s16x8 a;
            a = *(const s16x8*)&ckF[0 * 512 + lane * 8];
            acc0 = __builtin_amdgcn_mfma_f32_16x16x32_bf16(a, bf0, acc0, 0, 0, 0);
            a = *(const s16x8*)&ckF[1 * 512 + lane * 8];
            acc0 = __builtin_amdgcn_mfma_f32_16x16x32_bf16(a, bf1, acc0, 0, 0, 0);
            a = *(const s16x8*)&ckF[2 * 512 + lane * 8];
            acc1 = __builtin_amdgcn_mfma_f32_16x16x32_bf16(a, bf0, acc1, 0, 0, 0);
            a = *(const s16x8*)&ckF[3 * 512 + lane * 8];
            acc1 = __builtin_amdgcn_mfma_f32_16x16x32_bf16(a, bf1, acc1, 0, 0, 0);
            a = *(const s16x8*)&ckF[4 * 512 + lane * 8];
            acc2 = __builtin_amdgcn_mfma_f32_16x16x32_bf16(a, bf0, acc2, 0, 0, 0);
            a = *(const s16x8*)&ckF[5 * 512 + lane * 8];
            acc2 = __builtin_amdgcn_mfma_f32_16x16x32_bf16(a, bf1, acc2, 0, 0, 0);
            a = *(const s16x8*)&ckF[6 * 512 + lane * 8];
            acc3 = __builtin_amdgcn_mfma_f32_16x16x32_bf16(a, bf0, acc3, 0, 0, 0);
            a = *(const s16x8*)&ckF[7 * 512 + lane * 8];
            acc3 = __builtin_amdgcn_mfma_f32_16x16x32_bf16(a, bf1, acc3, 0, 0, 0);
        }

        // ---- band-sum (xor-reduce over k-quads), z row -> zb ----
        const float inv = sh_inv4[it];
        const int qq = kq;
        float rb[4][4];
#pragma unroll
        for (int mt = 0; mt < 4; ++mt) {
            f32x4 av = (mt == 0) ? acc0 : (mt == 1) ? acc1 : (mt == 2) ? acc2 : acc3;
            const float y0 = av[0] * inv, y1 = av[1] * inv;
            const float y2 = av[2] * inv, y3 = av[3] * inv;
            const float sA = y0 * y0;
            const float sB = y1 * y1 + y2 * y2 + y3 * y3;
            const float sAll = sA + sB;
            float b0 = (qq == 0) ? sA : 0.0f;
            float b1 = (qq == 0) ? sB : 0.0f;
            float b2 = (qq == 1) ? sAll : ((qq == 2) ? sA : 0.0f);
            float b3 = (qq == 3) ? sAll : ((qq == 2) ? sB : 0.0f);
            b0 += __shfl_xor(b0, 16); b0 += __shfl_xor(b0, 32);
            b1 += __shfl_xor(b1, 16); b1 += __shfl_xor(b1, 32);
            b2 += __shfl_xor(b2, 16); b2 += __shfl_xor(b2, 32);
            b3 += __shfl_xor(b3, 16); b3 += __shfl_xor(b3, 32);
            rb[mt][0] = b0; rb[mt][1] = b1; rb[mt][2] = b2; rb[mt][3] = b3;
        }
        float s0 = rb[0][0], s1 = rb[0][1], s2 = rb[0][2], s3 = rb[0][3];
#pragma unroll
        for (int mt = 1; mt < 4; ++mt) {
            s0 = (qq == mt) ? rb[mt][0] : s0;
            s1 = (qq == mt) ? rb[mt][1] : s1;
            s2 = (qq == mt) ? rb[mt][2] : s2;
            s3 = (qq == mt) ? rb[mt][3] : s3;
        }
        s16x4 zv;
        zv[0] = f2bf(sqrtf(fmaxf(s0, 1e-4f)));
        zv[1] = f2bf(sqrtf(fmaxf(s1, 1e-4f)));
        zv[2] = f2bf(sqrtf(fmaxf(s2, 1e-4f)));
        zv[3] = f2bf(sqrtf(fmaxf(s3, 1e-4f)));
        const int c = wv * 16 + ln15;
        *(s16x4*)&zb[it * 1032 + c * 16 + qq * 4] = zv;

        if (it < 3) __syncthreads();   // protect ckF overwrite
    }
    __syncthreads();   // all z rows ready

    // ---- epilogue: out[i] = sum_j W[i][j] z[j] via MFMA, 4 points batched ----
    const int mt5 = wv;
    const int g   = ln15 & 3;
    f32x4 acc5 = {0.f, 0.f, 0.f, 0.f};
#pragma unroll 4
    for (int st = 0; st < 32; ++st) {
        const s16x8 a  = *(const s16x8*)&Wfrag[((mt5 * 32 + st) * 64 + lane) * 8];
        const s16x8 zf = *(const s16x8*)&zb[g * 1032 + st * 32 + kq * 8];
        acc5 = __builtin_amdgcn_mfma_f32_16x16x32_bf16(a, zf, acc5, 0, 0, 0);
    }
    if (ln15 < 4) {
        const int i0 = mt5 * 16 + kq * 4;
        const int orow = (blockIdx.x * 4 + g) * CH;
#pragma unroll
        for (int rg = 0; rg < 4; ++rg)
            out[orow + i0 + rg] = acc5[rg] + biases[i0 + rg];
    }
}

extern "C" void kernel_launch(void* const* d_in, const int* in_sizes, int n_in,
                              void* d_out, int out_size, void* d_ws, size_t ws_size,
                              hipStream_t stream) {
    const float* xyz    = (const float*)d_in[0];
    const float* signal = (const float*)d_in[1];
    const float* weight = (const float*)d_in[2];
    const float* biases = (const float*)d_in[3];
    float* out = (float*)d_out;

    char* ws = (char*)d_ws;
    int*            knn_idx = (int*)ws;                          // 2 MB
    short*          Wfrag   = (short*)(ws + 0x200000);           // 128 KB
    float4*         xyz4    = (float4*)(ws + 0x220000);          // 128 KB
    unsigned short* sigbf   = (unsigned short*)(ws + 0x240000);  // 1 MB

    prep_kernel<<<128, 256, 0, stream>>>(weight, Wfrag, xyz, xyz4, signal, sigbf);
    knn_kernel<<<NB * NPTS, 256, 0, stream>>>(xyz4, knn_idx);
    conv_kernel<<<(NB * NPTS) / 4, 256, 0, stream>>>(xyz4, sigbf, Wfrag, biases,
                                                     knn_idx, out);
}